// Round 11
// baseline (178.026 us; speedup 1.0000x reference)
//
#include <hip/hip_runtime.h>

// Gated SPN, reverse scan over W:
//   h(i,t) = a*x + g1*h(i-1,t+1) + g2*h(i,t+1) + g3*h(i+1,t+1), a = 1-g1-g2-g3
//
// r11 = r10 (WT=32 cols, fp16-packed coeff tile, per-wave 16-row halo cones,
// 2 W-chunks x 128 slices = 256 blocks = 1/CU, non-draining LDS barriers)
// + tightened pipeline:
//  - per-round stage->reload interleave: round j of tile t is staged to LDS,
//    then R[j] is immediately reloaded with tile t+1 (WAR dependence pins the
//    load at the consumption point; asm "memory" barriers stop sinking).
//    Loads now fly ~a full tile period instead of scan-only.
//  - half-A outputs stored right after scan half A (frees registers, removes
//    a serialization point).
//  - branchless clamped reload on the last tile (single basic block).

#define HH 512
#define WW 512
#define WT 32
#define NT 1024            // 16 waves
#define ROWSP 545          // half4 row pitch: 16 halo + 512 + 16 halo + 1 pad
#define HLN 544

typedef _Float16 half4_t __attribute__((ext_vector_type(4)));

struct Regs { float4 x[4], g1[4], g2[4], g3[4]; };   // 4 rounds x 128 rows

__device__ __forceinline__ float dpp_prev(float v) {   // lane i <- lane i-1
    return __int_as_float(__builtin_amdgcn_update_dpp(
        0, __float_as_int(v), 0x138, 0xf, 0xf, false)); // wave_shr:1
}
__device__ __forceinline__ float dpp_next(float v) {   // lane i <- lane i+1
    return __int_as_float(__builtin_amdgcn_update_dpp(
        0, __float_as_int(v), 0x130, 0xf, 0xf, false)); // wave_shl:1
}

// LDS-only barrier: drains lgkm (ds_write visibility) but leaves vmem loads
// in flight. The asm "memory" clobber also blocks IR-level motion of global
// loads across it (the only pinning that provably holds).
__device__ __forceinline__ void lds_barrier() {
    asm volatile("s_waitcnt lgkmcnt(0)" ::: "memory");
    __builtin_amdgcn_s_barrier();
    __builtin_amdgcn_sched_barrier(0);
}

__device__ __forceinline__ void norm_store(half4_t* __restrict__ tile, int w, int r,
                                           float xx, float g1, float g2, float g3)
{
    const float sa = fabsf(g1) + fabsf(g2) + fabsf(g3);
    const float sc = (sa >= 1.0f) ? (1.0f / sa) : 1.0f;
    const float n1 = g1 * sc, n2 = g2 * sc, n3 = g3 * sc;
    const float a  = 1.0f - n1 - n2 - n3;
    half4_t v;
    v.x = (_Float16)(a * xx);
    v.y = (_Float16)n1;
    v.z = (_Float16)n2;
    v.w = (_Float16)n3;
    tile[w * ROWSP + (r + 16)] = v;
}

__global__ __launch_bounds__(NT, 4) void spn_kernel(
    const float* __restrict__ X, const float* __restrict__ G1,
    const float* __restrict__ G2, const float* __restrict__ G3,
    float* __restrict__ OUT)
{
    extern __shared__ char smem[];
    half4_t* tile = (half4_t*)smem;                                        // [WT][ROWSP]
    float*   hl0  = (float*)(smem + (size_t)WT * ROWSP * sizeof(half4_t)); // [HLN] x2
    float*   hl1  = hl0 + HLN;

    const int tid  = threadIdx.x;
    const int wv   = tid >> 6;
    const int lane = tid & 63;
    const int cidx = 32 * wv + lane;        // cone row + 16, in [0, 544)
    const int row  = cidx - 16;             // cone row in [-16, 528)
    const bool owned = (lane >= 16) && (lane < 48);
    const int lrow0 = tid >> 3;             // 8 lanes per row (128B), 4 rounds (+128j)
    const int lq    = tid & 7;              // 16B eighth of the 128B row segment

    const int slice = blockIdx.x >> 1;
    const int ch    = blockIdx.x & 1;
    const int cend       = ch ? WW : 288;   // scan region right edge
    const int ntiles     = ch ? 8 : 9;      // 32-col tiles
    const int warm_tiles = ch ? 0 : 1;      // ch0's first tile is warmup

    const size_t base = (size_t)slice * (size_t)(HH * WW);
    const float* Xp  = X  + base;
    const float* G1p = G1 + base;
    const float* G2p = G2 + base;
    const float* G3p = G3 + base;
    float* Op = OUT + base;

    // zero tile halo rows (32 w-slots x 16 rows each side) + h-lines;
    // visible at the first staging barrier
    if (tid < 512) {
        const int w = tid >> 4, rr = tid & 15;
        half4_t z; z.x = (_Float16)0; z.y = (_Float16)0; z.z = (_Float16)0; z.w = (_Float16)0;
        tile[w * ROWSP + rr]       = z;    // rows -16..-1
        tile[w * ROWSP + 528 + rr] = z;    // rows 512..527
    }
    if (tid < HLN) { hl0[tid] = 0.0f; hl1[tid] = 0.0f; }

    Regs R;
    {   // prologue: load tile 0 (rightmost)
        #pragma unroll
        for (int j = 0; j < 4; ++j) {
            const size_t off = (size_t)(lrow0 + j * 128) * WW
                             + (size_t)(cend - WT + lq * 4);
            R.x[j]  = *(const float4*)(Xp  + off);
            R.g1[j] = *(const float4*)(G1p + off);
            R.g2[j] = *(const float4*)(G2p + off);
            R.g3[j] = *(const float4*)(G3p + off);
        }
    }

    for (int t = 0; t < ntiles; ++t) {
        const int w0 = cend - WT * (t + 1);
        const bool emit = (t >= warm_tiles);
        // branchless clamp: last tile re-reads itself (L2-hot, discarded)
        const int w0n = (t + 1 < ntiles) ? (w0 - WT) : w0;

        // ---- per-round: stage tile t, then reload R[j] with tile t+1.
        //      WAR on R[j] pins the reload at/above the consumption point;
        //      loads then fly across scan A + B + stores (~full period). ----
        #pragma unroll
        for (int j = 0; j < 4; ++j) {
            const int r  = lrow0 + j * 128;
            const int wb = lq * 4;
            norm_store(tile, wb + 0, r, R.x[j].x, R.g1[j].x, R.g2[j].x, R.g3[j].x);
            norm_store(tile, wb + 1, r, R.x[j].y, R.g1[j].y, R.g2[j].y, R.g3[j].y);
            norm_store(tile, wb + 2, r, R.x[j].z, R.g1[j].z, R.g2[j].z, R.g3[j].z);
            norm_store(tile, wb + 3, r, R.x[j].w, R.g1[j].w, R.g2[j].w, R.g3[j].w);
            const size_t off = (size_t)r * WW + (size_t)(w0n + lq * 4);
            R.x[j]  = *(const float4*)(Xp  + off);
            R.g1[j] = *(const float4*)(G1p + off);
            R.g2[j] = *(const float4*)(G2p + off);
            R.g3[j] = *(const float4*)(G3p + off);
        }
        lds_barrier();   // tile visible; vmem loads NOT drained

        // ---- half A: 16 barrier-free steps, cols w0+31 .. w0+16 ----
        float hvA[16];
        {
            float h = hl0[cidx];
            #pragma unroll
            for (int s = 0; s < 16; ++s) {
                const int q = 31 - s;
                const half4_t v = tile[q * ROWSP + cidx];
                const float hu = dpp_prev(h);
                const float hd = dpp_next(h);
                h = fmaf((float)v.y, hu,
                    fmaf((float)v.z, h,
                    fmaf((float)v.w, hd, (float)v.x)));
                hvA[q - 16] = h;
            }
            if (owned) hl1[cidx] = h;   // re-anchor line for half B
        }
        // store half A now (global stores don't need the LDS barrier)
        if (owned && emit) {
            #pragma unroll
            for (int j = 0; j < 4; ++j) {
                const float4 o = make_float4(hvA[4 * j + 0], hvA[4 * j + 1],
                                             hvA[4 * j + 2], hvA[4 * j + 3]);
                *(float4*)(Op + (size_t)row * WW + (size_t)(w0 + 16 + 4 * j)) = o;
            }
        }
        lds_barrier();   // hl1 visible

        // ---- half B: 16 barrier-free steps, cols w0+15 .. w0 ----
        float hvB[16];
        {
            float h = hl1[cidx];
            #pragma unroll
            for (int s = 0; s < 16; ++s) {
                const int q = 15 - s;
                const half4_t v = tile[q * ROWSP + cidx];
                const float hu = dpp_prev(h);
                const float hd = dpp_next(h);
                h = fmaf((float)v.y, hu,
                    fmaf((float)v.z, h,
                    fmaf((float)v.w, hd, (float)v.x)));
                hvB[q] = h;
            }
            if (owned) hl0[cidx] = h;   // state for next tile
        }
        if (owned && emit) {
            #pragma unroll
            for (int j = 0; j < 4; ++j) {
                const float4 o = make_float4(hvB[4 * j + 0], hvB[4 * j + 1],
                                             hvB[4 * j + 2], hvB[4 * j + 3]);
                *(float4*)(Op + (size_t)row * WW + (size_t)(w0 + 4 * j)) = o;
            }
        }
        lds_barrier();   // hl0 publish visible + tile rewrite safe
    }
}

extern "C" void kernel_launch(void* const* d_in, const int* in_sizes, int n_in,
                              void* d_out, int out_size, void* d_ws, size_t ws_size,
                              hipStream_t stream) {
    const float* X  = (const float*)d_in[0];
    const float* G1 = (const float*)d_in[1];
    const float* G2 = (const float*)d_in[2];
    const float* G3 = (const float*)d_in[3];
    float* OUT = (float*)d_out;

    const int nblocks = 4 * 32 * 2;   // 128 slices x 2 W-chunks = 256 = #CUs
    const size_t smem = (size_t)WT * ROWSP * sizeof(half4_t) + 2 * HLN * sizeof(float);

    (void)hipFuncSetAttribute((const void*)spn_kernel,
                              hipFuncAttributeMaxDynamicSharedMemorySize, (int)smem);

    spn_kernel<<<nblocks, NT, smem, stream>>>(X, G1, G2, G3, OUT);
}